// Round 9
// baseline (434.272 us; speedup 1.0000x reference)
//
#include <hip/hip_runtime.h>

#define NBV 64
#define HWN 196
#define LTN 32
#define DIM 768
#define NH 12
#define DHD 64
#define ATT_SCALE 0.125f

typedef __attribute__((ext_vector_type(8))) __bf16 bf16x8;
typedef __attribute__((ext_vector_type(4))) float f32x4;

static __device__ __forceinline__ unsigned short f2bf(float f) {
    union { float f; unsigned u; } v; v.f = f;
    unsigned r = v.u + 0x7FFFu + ((v.u >> 16) & 1u);
    return (unsigned short)(r >> 16);
}

#define MFMA16(a, b, c) __builtin_amdgcn_mfma_f32_16x16x32_bf16((a), (b), (c), 0, 0, 0)
#define GLOAD_LDS16(g, l)                                                      \
    __builtin_amdgcn_global_load_lds(                                          \
        (const __attribute__((address_space(1))) void*)(g),                    \
        (__attribute__((address_space(3))) void*)(l), 16, 0, 0)

// Shared K-tile compute body (R3-exact): 12 ds_read_b128 + 32 MFMA, setprio.
__device__ __forceinline__ void compute_tile(const unsigned short* sa,
                                             const unsigned short* sb,
                                             f32x4 (&acc)[8][4])
{
    bf16x8 af[8], bg[4];
#pragma unroll
    for (int m = 0; m < 4; ++m) af[m] = *(const bf16x8*)(sa + m * 512);
#pragma unroll
    for (int n = 0; n < 4; ++n) bg[n] = *(const bf16x8*)(sb + n * 512);
#pragma unroll
    for (int m = 4; m < 8; ++m) af[m] = *(const bf16x8*)(sa + m * 512);
    __builtin_amdgcn_s_setprio(1);
#pragma unroll
    for (int m = 0; m < 4; ++m)
#pragma unroll
        for (int n = 0; n < 4; ++n)
            acc[m][n] = MFMA16(bg[n], af[m], acc[m][n]);
    __builtin_amdgcn_s_setprio(0);
    __builtin_amdgcn_s_setprio(1);
#pragma unroll
    for (int m = 4; m < 8; ++m)
#pragma unroll
        for (int n = 0; n < 4; ++n)
            acc[m][n] = MFMA16(bg[n], af[m], acc[m][n]);
    __builtin_amdgcn_s_setprio(0);
}

// ---------------------------------------------------------------- convert ---
struct CvtCfg {
    const float* src[14];
    unsigned short* dst[14];
    int n4[14];
};

__global__ __launch_bounds__(256) void cvt_bf16(CvtCfg cfg) {
    const int e = blockIdx.y;
    const float4* s = (const float4*)cfg.src[e];
    unsigned short* d = cfg.dst[e];
    const int n4 = cfg.n4[e];
    for (int i = blockIdx.x * 256 + threadIdx.x; i < n4; i += gridDim.x * 256) {
        float4 v = s[i];
        ushort4 o;
        o.x = f2bf(v.x); o.y = f2bf(v.y); o.z = f2bf(v.z); o.w = f2bf(v.w);
        *(ushort4*)(d + (long)i * 4) = o;
    }
}

// ------------------------------------------------------------ GEMM probe ---
// DIAGNOSTIC: identical K-loop minus staging/vmcnt.  12 reps x 24 tiles,
// grid 256 (1 block/CU, one generation): dur_us*2400/288 = cyc per K-tile of
// the (ds_read + MFMA + barrier) component.  MFMAs kept live via checksum.
__global__ __launch_bounds__(512, 2) void gemm_probe(unsigned short* sink)
{
    __shared__ __align__(16) unsigned short lds[65536];
    const int tid = threadIdx.x;
    const int lane = tid & 63, wid = tid >> 6;
    const int wm = wid >> 2, wn = wid & 3;
    const int fr = lane & 15, fg = lane >> 4;
    const int rxor = (fg ^ ((fr >> 1) & 3)) * 8;
    const int aoff = (wm * 128 + fr) * 32 + rxor;
    const int boff = 8192 + (wn * 64 + fr) * 32 + rxor;

    f32x4 acc[8][4] = {};
#pragma unroll 1
    for (int rep = 0; rep < 12; ++rep) {
#pragma unroll 1
        for (int t = 0; t < 24; ++t) {
            __builtin_amdgcn_s_barrier();
            const unsigned short* base = lds + (t & 3) * 16384;
            compute_tile(base + aoff, base + boff, acc);
        }
    }
    float chk = 0.f;
#pragma unroll
    for (int m = 0; m < 8; ++m)
#pragma unroll
        for (int n = 0; n < 4; ++n)
#pragma unroll
            for (int j = 0; j < 4; ++j) chk += acc[m][n][j];
    if (chk == 12345.678f) sink[tid] = 1;   // never true; keeps MFMAs live
}

// ------------------------------------------------------------------- GEMM ---
// R3-exact (best measured: 138.3 us).  256x256 tile, BK=32, 8 waves, 4 slots,
// depth-3 prefetch, vmcnt(8), one barrier/K-tile, C^T frags, LDS epilogue.
struct GemmCfg {
    const unsigned short* A[2];
    const unsigned short* W[2];
    unsigned short* out[2];
    const float* bias[2][6];
    int M[2];
};

__global__ __launch_bounds__(512, 2) void gemm_proj(GemmCfg cfg, int nb0)
{
    __shared__ __align__(16) unsigned short lds[65536];   // 4 slots x 32 KiB
    const int tid = threadIdx.x;
    const int lane = tid & 63, wid = tid >> 6;
    const int wm = wid >> 2, wn = wid & 3;
    const int fr = lane & 15, fg = lane >> 4;

    const int nwg = gridDim.x;
    const int orig = blockIdx.x;
    const int q = nwg >> 3, r = nwg & 7;
    const int xcd = orig & 7, lid = orig >> 3;
    const int wg = (xcd < r ? xcd * (q + 1) : r * (q + 1) + (xcd - r) * q) + lid;

    const int set = wg >= nb0;
    const int local = wg - (set ? nb0 : 0);
    const int mt = local / 18, nt = local - mt * 18;
    const int m0 = mt * 256, n0 = nt * 256;
    const int M = cfg.M[set];
    const unsigned short* __restrict__ A = cfg.A[set];
    const unsigned short* __restrict__ W = cfg.W[set];

    const int srow = tid >> 2;
    const int sxor = ((tid & 3) ^ ((tid >> 3) & 3)) * 8;
    const unsigned short* aSrc = A + (long)(m0 + srow) * DIM + sxor;
    const unsigned short* bSrc = W + (long)(n0 + srow) * DIM + sxor;
    unsigned short* ldst = lds + tid * 8;

    const int rxor = (fg ^ ((fr >> 1) & 3)) * 8;
    const int aoff = (wm * 128 + fr) * 32 + rxor;
    const int boff = 8192 + (wn * 64 + fr) * 32 + rxor;

    f32x4 acc[8][4] = {};   // acc[m][n][j] = C[m*16+fr][n*16+fg*4+j]  (C^T frag)

#define STAGE(t, s) do {                                                       \
    const unsigned short* _a = aSrc + (t) * 32;                                \
    const unsigned short* _b = bSrc + (t) * 32;                                \
    unsigned short* _d = ldst + (s) * 16384;                                   \
    GLOAD_LDS16(_a, _d);                                                       \
    GLOAD_LDS16(_a + 98304, _d + 4096);                                        \
    GLOAD_LDS16(_b, _d + 8192);                                                \
    GLOAD_LDS16(_b + 98304, _d + 12288);                                       \
} while (0)

    STAGE(0, 0); STAGE(1, 1); STAGE(2, 2);
#pragma unroll 1
    for (int t = 0; t < 21; ++t) {                 // K=768 -> 24 tiles of 32
        asm volatile("s_waitcnt vmcnt(8)" ::: "memory");   // tile t landed
        __builtin_amdgcn_s_barrier();
        STAGE(t + 3, (t + 3) & 3);                 // slot of tile t-1: free
        {
            const unsigned short* base = lds + (t & 3) * 16384;
            compute_tile(base + aoff, base + boff, acc);
        }
    }
    asm volatile("s_waitcnt vmcnt(8)" ::: "memory");
    __builtin_amdgcn_s_barrier();
    { const unsigned short* base = lds + 16384;     compute_tile(base + aoff, base + boff, acc); }
    asm volatile("s_waitcnt vmcnt(4)" ::: "memory");
    __builtin_amdgcn_s_barrier();
    { const unsigned short* base = lds + 2 * 16384; compute_tile(base + aoff, base + boff, acc); }
    asm volatile("s_waitcnt vmcnt(0)" ::: "memory");
    __builtin_amdgcn_s_barrier();
    { const unsigned short* base = lds + 3 * 16384; compute_tile(base + aoff, base + boff, acc); }

#undef STAGE

    // ---- epilogue: bias + bf16, staged through LDS for coalesced stores ----
    const int w = nt / 3;
    const int nlb = (nt - w * 3) * 256;
    const float* bp = cfg.bias[set][w];
    unsigned short* op = cfg.out[set] + (long)w * M * DIM;
    const int colL = wn * 64;
    asm volatile("" ::: "memory");
    __builtin_amdgcn_s_barrier();                  // LDS reuse for C
#pragma unroll
    for (int p = 0; p < 2; ++p) {
        if (wm == p) {
#pragma unroll
            for (int n = 0; n < 4; ++n) {
                float4 b4 = *(const float4*)(bp + nlb + colL + n * 16 + fg * 4);
#pragma unroll
                for (int m = 0; m < 8; ++m) {
                    ushort4 u;
                    u.x = f2bf(acc[m][n][0] + b4.x);
                    u.y = f2bf(acc[m][n][1] + b4.y);
                    u.z = f2bf(acc[m][n][2] + b4.z);
                    u.w = f2bf(acc[m][n][3] + b4.w);
                    *(ushort4*)&lds[(m * 16 + fr) * 264 + colL + n * 16 + fg * 4] = u;
                }
            }
        }
        __builtin_amdgcn_s_barrier();
#pragma unroll
        for (int i = 0; i < 8; ++i) {
            int chunk = tid + i * 512;             // 4096 chunks = 128x256
            int rr = chunk >> 5, cb = chunk & 31;
            bf16x8 v = *(const bf16x8*)&lds[rr * 264 + cb * 8];
            *(bf16x8*)(op + (long)(m0 + p * 128 + rr) * DIM + nlb + cb * 8) = v;
        }
        if (p == 0) __builtin_amdgcn_s_barrier();
    }
}

// -------------------------------------------------------------- transpose ---
struct TransCfg {
    const unsigned short* src[4];
    unsigned short* dst[4];
};

__global__ __launch_bounds__(256) void transpose_v(TransCfg cfg)
{
    __shared__ unsigned short t[32][33];
    const int x = blockIdx.x;
    const int which = x >> 3;
    const int xi = x & 7;
    const int istxt = (xi == 7);
    const unsigned short* src = cfg.src[which * 2 + istxt];
    unsigned short* dst = cfg.dst[which];
    const int nrows = istxt ? LTN : HWN;
    const int colbase = istxt ? 208 : 0;
    const int rt = istxt ? 0 : xi;

    const int bv = blockIdx.z, dt = blockIdx.y;
    const int tx = threadIdx.x & 31, ty = threadIdx.x >> 5;
#pragma unroll
    for (int i = 0; i < 4; ++i) {
        int r = rt * 32 + ty + i * 8;
        t[ty + i * 8][tx] = (r < nrows)
            ? src[(long)(bv * nrows + r) * DIM + dt * 32 + tx] : (unsigned short)0;
    }
    __syncthreads();
#pragma unroll
    for (int i = 0; i < 4; ++i) {
        int d = dt * 32 + ty + i * 8;
        int rr = rt * 32 + tx;
        if (rr < nrows)
            dst[(long)(bv * DIM + d) * 256 + colbase + rr] = t[tx][ty + i * 8];
    }
}

// -------------------------------------------------------------- attention ---
struct AttnCfg {
    const unsigned short* QA[2];
    const unsigned short* QB[2];
    const unsigned short* KV[2];
    const unsigned short* KT[2];
    const unsigned short* Vt[2];
    float* outp[2];
};

__global__ __launch_bounds__(256, 2) void attn_kernel(AttnCfg cfg,
                                                      const int* __restrict__ tmask)
{
    __shared__ __align__(16) unsigned short P[4][16][264];
    const int tid = threadIdx.x, lane = tid & 63, wid = tid >> 6;
    const int bv = blockIdx.x, h = blockIdx.y;
    const int b = bv >> 4;
    const int sel = (blockIdx.z == 4);
    const int nq = sel ? LTN : HWN;
    const unsigned short* QA = cfg.QA[sel];
    const unsigned short* QB = cfg.QB[sel];
    const unsigned short* KV = cfg.KV[sel];
    const unsigned short* KT = cfg.KT[sel];
    const unsigned short* Vt = cfg.Vt[sel];
    float* outp = cfg.outp[sel];
    const int q0 = (sel ? 0 : blockIdx.z * 64) + wid * 16;
    const int fr = lane & 15, fg = lane >> 4;

    int qr = q0 + fr; if (qr > nq - 1) qr = nq - 1;
    const unsigned short* qa_p = QA + (long)(bv * nq + qr) * DIM + h * DHD;
    const unsigned short* qb_p = QB + (long)(bv * nq + qr) * DIM + h * DHD;
    bf16x8 qa[2], qb[2];
#pragma unroll
    for (int kh = 0; kh < 2; ++kh) {
        qa[kh] = *(const bf16x8*)(qa_p + kh * 32 + fg * 8);
        qb[kh] = *(const bf16x8*)(qb_p + kh * 32 + fg * 8);
    }

    f32x4 acc[15];
#pragma unroll
    for (int kb = 0; kb < 13; ++kb) {
        int kr = kb * 16 + fr; if (kr > HWN - 1) kr = HWN - 1;
        const unsigned short* kp = KV + (long)(bv * HWN + kr) * DIM + h * DHD;
        f32x4 c = {0.f, 0.f, 0.f, 0.f};
        c = MFMA16(*(const bf16x8*)(kp + fg * 8), qa[0], c);
        c = MFMA16(*(const bf16x8*)(kp + 32 + fg * 8), qa[1], c);
        acc[kb] = c;
    }
#pragma unroll
    for (int kb = 13; kb < 15; ++kb) {
        int kr = (kb - 13) * 16 + fr;
        const unsigned short* kp = KT + (long)(bv * LTN + kr) * DIM + h * DHD;
        f32x4 c = {0.f, 0.f, 0.f, 0.f};
        c = MFMA16(*(const bf16x8*)(kp + fg * 8), qb[0], c);
        c = MFMA16(*(const bf16x8*)(kp + 32 + fg * 8), qb[1], c);
        acc[kb] = c;
    }

    int tm = tmask[b * LTN + (lane & 31)];
    bool vq = true;
    if (sel) {
        int qi = q0 + fr; if (qi > LTN - 1) qi = LTN - 1;
        vq = __shfl(tm, qi, 64) != 0;
    }
#pragma unroll
    for (int kb = 0; kb < 15; ++kb) {
#pragma unroll
        for (int j = 0; j < 4; ++j) {
            int c = kb * 16 + fg * 4 + j;
            bool kreal = (c < HWN) || (c >= 208);
            bool kvalid = true;
            if (c >= 208) kvalid = __shfl(tm, c - 208, 64) != 0;
            float l = acc[kb][j];
            if (!kreal) l = -3.0e38f;
            else if (!(kvalid && vq)) l = -10000.0f;
            acc[kb][j] = l;
        }
    }

    float mx = -3.0e38f;
#pragma unroll
    for (int kb = 0; kb < 15; ++kb)
#pragma unroll
        for (int j = 0; j < 4; ++j) mx = fmaxf(mx, acc[kb][j]);
    mx = fmaxf(mx, __shfl_xor(mx, 16, 64));
    mx = fmaxf(mx, __shfl_xor(mx, 32, 64));
    float s = 0.f;
#pragma unroll
    for (int kb = 0; kb < 15; ++kb)
#pragma unroll
        for (int j = 0; j < 4; ++j) {
            float p = __expf(acc[kb][j] - mx);
            acc[kb][j] = p;
            s += p;
        }
    s += __shfl_xor(s, 16, 64);
    s += __shfl_xor(s, 32, 64);

    unsigned short* pw = &P[wid][fr][0];
#pragma unroll
    for (int kb = 0; kb < 15; ++kb) {
        ushort4 u;
        u.x = f2bf(acc[kb][0]); u.y = f2bf(acc[kb][1]);
        u.z = f2bf(acc[kb][2]); u.w = f2bf(acc[kb][3]);
        *(ushort4*)(pw + kb * 16 + fg * 4) = u;
    }
    {
        ushort4 z = {0, 0, 0, 0};
        *(ushort4*)(pw + 240 + fg * 4) = z;
    }

    f32x4 oacc[4] = {};
    const unsigned short* vt_base = Vt + ((long)bv * DIM + h * DHD) * 256;
#pragma unroll
    for (int ks = 0; ks < 8; ++ks) {
        bf16x8 pf = *(const bf16x8*)(pw + ks * 32 + fg * 8);
#pragma unroll
        for (int n = 0; n < 4; ++n) {
            const unsigned short* vp = vt_base + (long)(n * 16 + fr) * 256 + ks * 32 + fg * 8;
            oacc[n] = MFMA16(*(const bf16x8*)vp, pf, oacc[n]);
        }
    }

    if (q0 + fr < nq) {
        float inv = ATT_SCALE / s;
        float* ob = outp + (long)(bv * nq + q0 + fr) * DIM + h * DHD;
#pragma unroll
        for (int n = 0; n < 4; ++n) {
            float4 o;
            o.x = oacc[n][0] * inv; o.y = oacc[n][1] * inv;
            o.z = oacc[n][2] * inv; o.w = oacc[n][3] * inv;
            *(float4*)(ob + n * 16 + fg * 4) = o;
        }
    }
}

// ----------------------------------------------------------------- launch ---
extern "C" void kernel_launch(void* const* d_in, const int* in_sizes, int n_in,
                              void* d_out, int out_size, void* d_ws, size_t ws_size,
                              hipStream_t stream)
{
    const float* vid_feat = (const float*)d_in[0];
    const float* txt_feat = (const float*)d_in[1];
    const int*   txt_mask = (const int*)d_in[3];
    const float* v2v_W = (const float*)d_in[4];
    const float* v2v_b = (const float*)d_in[5];
    const float* t2v_W = (const float*)d_in[6];
    const float* t2v_b = (const float*)d_in[7];
    const float* t2t_W = (const float*)d_in[8];
    const float* t2t_b = (const float*)d_in[9];
    const float* v2t_W = (const float*)d_in[10];
    const float* v2t_b = (const float*)d_in[11];

    char* ws = (char*)d_ws;
    unsigned short* vid_bf   = (unsigned short*)(ws);
    unsigned short* txt_bf   = (unsigned short*)(ws + 19267584L);
    unsigned short* Wv_bf    = (unsigned short*)(ws + 22413312L);
    unsigned short* Wt_bf    = (unsigned short*)(ws + 29491200L);
    unsigned short* proj_vid = (unsigned short*)(ws + 36569088L);
    unsigned short* proj_txt = (unsigned short*)(ws + 152174592L);
    unsigned short* Vt_v     = (unsigned short*)(ws + 171048960L);
    unsigned short* Vt_t     = (unsigned short*)(ws + 196214784L);

    // DIAGNOSTIC probe: per-block (ds_read+MFMA+barrier) time, 1 generation.
    gemm_probe<<<dim3(256), 512, 0, stream>>>(proj_vid);

    const long WSL = 589824;  // one 768x768 weight slice (elements)
    CvtCfg cc;
    cc.src[0] = vid_feat; cc.dst[0] = vid_bf; cc.n4[0] = 9633792 / 4;
    cc.src[1] = txt_feat; cc.dst[1] = txt_bf; cc.n4[1] = 1572864 / 4;
    const float* wsrc_v[6] = { v2v_W, v2v_W + WSL, t2v_W, v2t_W + WSL,
                               v2v_W + 2 * WSL, v2t_W + 2 * WSL };
    const float* wsrc_t[6] = { t2v_W + WSL, t2v_W + 2 * WSL, v2t_W, t2t_W,
                               t2t_W + WSL, t2t_W + 2 * WSL };
    for (int i = 0; i < 6; ++i) {
        cc.src[2 + i] = wsrc_v[i]; cc.dst[2 + i] = Wv_bf + (long)i * WSL; cc.n4[2 + i] = WSL / 4;
        cc.src[8 + i] = wsrc_t[i]; cc.dst[8 + i] = Wt_bf + (long)i * WSL; cc.n4[8 + i] = WSL / 4;
    }
    cvt_bf16<<<dim3(2048, 14), 256, 0, stream>>>(cc);

    GemmCfg gc;
    gc.A[0] = vid_bf;  gc.W[0] = Wv_bf;  gc.out[0] = proj_vid;  gc.M[0] = 12544;
    gc.A[1] = txt_bf;  gc.W[1] = Wt_bf;  gc.out[1] = proj_txt;  gc.M[1] = 2048;
    const float* bsrc_v[6] = { v2v_b, v2v_b + 768, t2v_b, v2t_b + 768,
                               v2v_b + 1536, v2t_b + 1536 };
    const float* bsrc_t[6] = { t2v_b + 768, t2v_b + 1536, v2t_b, t2t_b,
                               t2t_b + 768, t2t_b + 1536 };
    for (int i = 0; i < 6; ++i) { gc.bias[0][i] = bsrc_v[i]; gc.bias[1][i] = bsrc_t[i]; }
    gemm_proj<<<dim3(49 * 18 + 8 * 18), 512, 0, stream>>>(gc, 49 * 18);

    const long PV = 12544L * 768, PT = 2048L * 768;
    TransCfg tc;
    tc.src[0] = proj_vid + 4 * PV;  tc.src[1] = proj_txt + 1 * PT;  tc.dst[0] = Vt_v;
    tc.src[2] = proj_vid + 5 * PV;  tc.src[3] = proj_txt + 5 * PT;  tc.dst[1] = Vt_t;
    transpose_v<<<dim3(16, 24, 64), 256, 0, stream>>>(tc);

    float* out_f = (float*)d_out;
    AttnCfg ac;
    ac.QA[0] = proj_vid + 0 * PV;  ac.QB[0] = proj_vid + 2 * PV;
    ac.KV[0] = proj_vid + 1 * PV;  ac.KT[0] = proj_txt + 0 * PT;
    ac.Vt[0] = Vt_v;               ac.outp[0] = out_f;
    ac.QA[1] = proj_txt + 2 * PT;  ac.QB[1] = proj_txt + 3 * PT;
    ac.KV[1] = proj_vid + 3 * PV;  ac.KT[1] = proj_txt + 4 * PT;
    ac.Vt[1] = Vt_t;               ac.outp[1] = out_f + 9633792;
    attn_kernel<<<dim3(64, 12, 5), 256, 0, stream>>>(ac, txt_mask);
}

// Round 10
// 304.877 us; speedup vs baseline: 1.4244x; 1.4244x over previous
//
#include <hip/hip_runtime.h>

#define NBV 64
#define HWN 196
#define LTN 32
#define DIM 768
#define NH 12
#define DHD 64
#define ATT_SCALE 0.125f

typedef __attribute__((ext_vector_type(8))) __bf16 bf16x8;
typedef __attribute__((ext_vector_type(4))) float f32x4;

static __device__ __forceinline__ unsigned short f2bf(float f) {
    union { float f; unsigned u; } v; v.f = f;
    unsigned r = v.u + 0x7FFFu + ((v.u >> 16) & 1u);
    return (unsigned short)(r >> 16);
}

#define MFMA16(a, b, c) __builtin_amdgcn_mfma_f32_16x16x32_bf16((a), (b), (c), 0, 0, 0)
#define GLOAD_LDS16(g, l)                                                      \
    __builtin_amdgcn_global_load_lds(                                          \
        (const __attribute__((address_space(1))) void*)(g),                    \
        (__attribute__((address_space(3))) void*)(l), 16, 0, 0)

// ---------------------------------------------------------------- convert ---
struct CvtCfg {
    const float* src[14];
    unsigned short* dst[14];
    int n4[14];
};

__global__ __launch_bounds__(256) void cvt_bf16(CvtCfg cfg) {
    const int e = blockIdx.y;
    const float4* s = (const float4*)cfg.src[e];
    unsigned short* d = cfg.dst[e];
    const int n4 = cfg.n4[e];
    for (int i = blockIdx.x * 256 + threadIdx.x; i < n4; i += gridDim.x * 256) {
        float4 v = s[i];
        ushort4 o;
        o.x = f2bf(v.x); o.y = f2bf(v.y); o.z = f2bf(v.z); o.w = f2bf(v.w);
        *(ushort4*)(d + (long)i * 4) = o;
    }
}

// ------------------------------------------------------------------- GEMM ---
// R10: 128x128 tile, 4 waves (2x2), BK=32, 3 LDS slots x 16 KiB (48 KiB) ->
// 3 blocks/CU.  Probe (R9) showed compute side = MFMA floor (85% MfmaUtil);
// the 2300 cyc/tile staging stall needs CROSS-BLOCK overlap (m114), which the
// 256^2 tile forbade (1 block/CU).  Depth-2 prefetch, vmcnt(4), R3 sync
// algebra, source-side swizzle, C^T frags + single-pass LDS epilogue.
struct GemmCfg {
    const unsigned short* A[2];
    const unsigned short* W[2];
    unsigned short* out[2];
    const float* bias[2][6];
    int M[2];
};

__global__ __launch_bounds__(256, 3) void gemm_proj(GemmCfg cfg, int nb0)
{
    __shared__ __align__(16) unsigned short lds[24576];   // 3 slots x 8192 elems
    const int tid = threadIdx.x;
    const int lane = tid & 63, wid = tid >> 6;
    const int wm = wid >> 1, wn = wid & 1;
    const int fr = lane & 15, fg = lane >> 4;

    // T1: bijective XCD swizzle (m204)
    const int nwg = gridDim.x;
    const int orig = blockIdx.x;
    const int q = nwg >> 3, r = nwg & 7;
    const int xcd = orig & 7, lid = orig >> 3;
    const int wg = (xcd < r ? xcd * (q + 1) : r * (q + 1) + (xcd - r) * q) + lid;

    const int set = wg >= nb0;
    const int local = wg - (set ? nb0 : 0);
    const int mt = local / 36, nt = local - mt * 36;
    const int m0 = mt * 128, n0 = nt * 128;
    const int M = cfg.M[set];
    const unsigned short* __restrict__ A = cfg.A[set];
    const unsigned short* __restrict__ W = cfg.W[set];

    // staging: thread -> (row = tid>>2 [0..63, +64], granule = tid&3);
    // source pre-swizzled: LDS[row][g] holds k-granule g ^ ((row>>1)&3)
    const int srow = tid >> 2;
    const int sxor = ((tid & 3) ^ ((tid >> 3) & 3)) * 8;
    const unsigned short* aSrc = A + (long)(m0 + srow) * DIM + sxor;
    const unsigned short* bSrc = W + (long)(n0 + srow) * DIM + sxor;
    unsigned short* ldst = lds + tid * 8;

    const int rxor = (fg ^ ((fr >> 1) & 3)) * 8;
    const int aoff = fr * 32 + rxor;                  // + m*512
    const int boff = 4096 + (wn * 64 + fr) * 32 + rxor;

    f32x4 acc[4][4] = {};   // acc[m][n][j] = C[wm*64+m*16+fr][wn*64+n*16+fg*4+j]

#define STAGE(t, s) do {                                                       \
    const unsigned short* _a = aSrc + (t) * 32;                                \
    const unsigned short* _b = bSrc + (t) * 32;                                \
    unsigned short* _d = ldst + (s) * 8192;                                    \
    GLOAD_LDS16(_a, _d);                                                       \
    GLOAD_LDS16(_a + 49152, _d + 2048);                                        \
    GLOAD_LDS16(_b, _d + 4096);                                                \
    GLOAD_LDS16(_b + 49152, _d + 6144);                                        \
} while (0)

#define WAITVM(n) asm volatile("s_waitcnt vmcnt(" #n ")" ::: "memory")

#define COMPUTE(s) do {                                                        \
    const unsigned short* _sa = lds + (s) * 8192 + (wm * 64) * 32 + aoff;      \
    const unsigned short* _sb = lds + (s) * 8192 + boff;                       \
    bf16x8 af[4], bg[4];                                                       \
    _Pragma("unroll") for (int m = 0; m < 4; ++m)                              \
        af[m] = *(const bf16x8*)(_sa + m * 512);                               \
    _Pragma("unroll") for (int n = 0; n < 4; ++n)                              \
        bg[n] = *(const bf16x8*)(_sb + n * 512);                               \
    __builtin_amdgcn_s_setprio(1);                                             \
    _Pragma("unroll") for (int m = 0; m < 4; ++m)                              \
    _Pragma("unroll") for (int n = 0; n < 4; ++n)                              \
        acc[m][n] = MFMA16(bg[n], af[m], acc[m][n]);                           \
    __builtin_amdgcn_s_setprio(0);                                             \
} while (0)

    STAGE(0, 0); STAGE(1, 1);
    {
        int s0 = 0, s2 = 2;                        // s0 = t%3, s2 = (t+2)%3
#pragma unroll 1
        for (int t = 0; t < 22; ++t) {             // K=768 -> 24 tiles of 32
            WAITVM(4);                             // tile t landed
            __builtin_amdgcn_s_barrier();
            STAGE(t + 2, s2);                      // slot of tile t-1: free
            COMPUTE(s0);
            s0 = s0 == 2 ? 0 : s0 + 1;
            s2 = s2 == 2 ? 0 : s2 + 1;
        }
        WAITVM(4);
        __builtin_amdgcn_s_barrier();
        COMPUTE(s0);                               // tile 22 (slot 1)
        s0 = s0 == 2 ? 0 : s0 + 1;
        WAITVM(0);
        __builtin_amdgcn_s_barrier();
        COMPUTE(s0);                               // tile 23 (slot 2)
    }

#undef COMPUTE
#undef WAITVM
#undef STAGE

    // ---- epilogue: bias + bf16 via LDS [128][132], single pass ----
    const int w = nt / 6;
    const int nlb = (nt - w * 6) * 128;
    const float* bp = cfg.bias[set][w];
    unsigned short* op = cfg.out[set] + (long)w * M * DIM;
    asm volatile("" ::: "memory");
    __builtin_amdgcn_s_barrier();                  // LDS reuse for C
#pragma unroll
    for (int n = 0; n < 4; ++n) {
        float4 b4 = *(const float4*)(bp + nlb + wn * 64 + n * 16 + fg * 4);
#pragma unroll
        for (int m = 0; m < 4; ++m) {
            ushort4 u;
            u.x = f2bf(acc[m][n][0] + b4.x);
            u.y = f2bf(acc[m][n][1] + b4.y);
            u.z = f2bf(acc[m][n][2] + b4.z);
            u.w = f2bf(acc[m][n][3] + b4.w);
            *(ushort4*)&lds[(wm * 64 + m * 16 + fr) * 132 + wn * 64 + n * 16 + fg * 4] = u;
        }
    }
    __builtin_amdgcn_s_barrier();
#pragma unroll
    for (int i = 0; i < 8; ++i) {
        int chunk = tid + i * 256;                 // 2048 chunks = 128x128
        int rr = chunk >> 4, cb = chunk & 15;
        bf16x8 v = *(const bf16x8*)&lds[rr * 132 + cb * 8];
        *(bf16x8*)(op + (long)(m0 + rr) * DIM + nlb + cb * 8) = v;
    }
}

// -------------------------------------------------------------- transpose ---
struct TransCfg {
    const unsigned short* src[4];
    unsigned short* dst[4];
};

__global__ __launch_bounds__(256) void transpose_v(TransCfg cfg)
{
    __shared__ unsigned short t[32][33];
    const int x = blockIdx.x;
    const int which = x >> 3;
    const int xi = x & 7;
    const int istxt = (xi == 7);
    const unsigned short* src = cfg.src[which * 2 + istxt];
    unsigned short* dst = cfg.dst[which];
    const int nrows = istxt ? LTN : HWN;
    const int colbase = istxt ? 208 : 0;
    const int rt = istxt ? 0 : xi;

    const int bv = blockIdx.z, dt = blockIdx.y;
    const int tx = threadIdx.x & 31, ty = threadIdx.x >> 5;
#pragma unroll
    for (int i = 0; i < 4; ++i) {
        int r = rt * 32 + ty + i * 8;
        t[ty + i * 8][tx] = (r < nrows)
            ? src[(long)(bv * nrows + r) * DIM + dt * 32 + tx] : (unsigned short)0;
    }
    __syncthreads();
#pragma unroll
    for (int i = 0; i < 4; ++i) {
        int d = dt * 32 + ty + i * 8;
        int rr = rt * 32 + tx;
        if (rr < nrows)
            dst[(long)(bv * DIM + d) * 256 + colbase + rr] = t[tx][ty + i * 8];
    }
}

// -------------------------------------------------------------- attention ---
struct AttnCfg {
    const unsigned short* QA[2];
    const unsigned short* QB[2];
    const unsigned short* KV[2];
    const unsigned short* KT[2];
    const unsigned short* Vt[2];
    float* outp[2];
};

__global__ __launch_bounds__(256, 2) void attn_kernel(AttnCfg cfg,
                                                      const int* __restrict__ tmask)
{
    __shared__ __align__(16) unsigned short P[4][16][264];
    const int tid = threadIdx.x, lane = tid & 63, wid = tid >> 6;
    const int bv = blockIdx.x, h = blockIdx.y;
    const int b = bv >> 4;
    const int sel = (blockIdx.z == 4);
    const int nq = sel ? LTN : HWN;
    const unsigned short* QA = cfg.QA[sel];
    const unsigned short* QB = cfg.QB[sel];
    const unsigned short* KV = cfg.KV[sel];
    const unsigned short* KT = cfg.KT[sel];
    const unsigned short* Vt = cfg.Vt[sel];
    float* outp = cfg.outp[sel];
    const int q0 = (sel ? 0 : blockIdx.z * 64) + wid * 16;
    const int fr = lane & 15, fg = lane >> 4;

    int qr = q0 + fr; if (qr > nq - 1) qr = nq - 1;
    const unsigned short* qa_p = QA + (long)(bv * nq + qr) * DIM + h * DHD;
    const unsigned short* qb_p = QB + (long)(bv * nq + qr) * DIM + h * DHD;
    bf16x8 qa[2], qb[2];
#pragma unroll
    for (int kh = 0; kh < 2; ++kh) {
        qa[kh] = *(const bf16x8*)(qa_p + kh * 32 + fg * 8);
        qb[kh] = *(const bf16x8*)(qb_p + kh * 32 + fg * 8);
    }

    f32x4 acc[15];
#pragma unroll
    for (int kb = 0; kb < 13; ++kb) {
        int kr = kb * 16 + fr; if (kr > HWN - 1) kr = HWN - 1;
        const unsigned short* kp = KV + (long)(bv * HWN + kr) * DIM + h * DHD;
        f32x4 c = {0.f, 0.f, 0.f, 0.f};
        c = MFMA16(*(const bf16x8*)(kp + fg * 8), qa[0], c);
        c = MFMA16(*(const bf16x8*)(kp + 32 + fg * 8), qa[1], c);
        acc[kb] = c;
    }
#pragma unroll
    for (int kb = 13; kb < 15; ++kb) {
        int kr = (kb - 13) * 16 + fr;
        const unsigned short* kp = KT + (long)(bv * LTN + kr) * DIM + h * DHD;
        f32x4 c = {0.f, 0.f, 0.f, 0.f};
        c = MFMA16(*(const bf16x8*)(kp + fg * 8), qb[0], c);
        c = MFMA16(*(const bf16x8*)(kp + 32 + fg * 8), qb[1], c);
        acc[kb] = c;
    }

    int tm = tmask[b * LTN + (lane & 31)];
    bool vq = true;
    if (sel) {
        int qi = q0 + fr; if (qi > LTN - 1) qi = LTN - 1;
        vq = __shfl(tm, qi, 64) != 0;
    }
#pragma unroll
    for (int kb = 0; kb < 15; ++kb) {
#pragma unroll
        for (int j = 0; j < 4; ++j) {
            int c = kb * 16 + fg * 4 + j;
            bool kreal = (c < HWN) || (c >= 208);
            bool kvalid = true;
            if (c >= 208) kvalid = __shfl(tm, c - 208, 64) != 0;
            float l = acc[kb][j];
            if (!kreal) l = -3.0e38f;
            else if (!(kvalid && vq)) l = -10000.0f;
            acc[kb][j] = l;
        }
    }

    float mx = -3.0e38f;
#pragma unroll
    for (int kb = 0; kb < 15; ++kb)
#pragma unroll
        for (int j = 0; j < 4; ++j) mx = fmaxf(mx, acc[kb][j]);
    mx = fmaxf(mx, __shfl_xor(mx, 16, 64));
    mx = fmaxf(mx, __shfl_xor(mx, 32, 64));
    float s = 0.f;
#pragma unroll
    for (int kb = 0; kb < 15; ++kb)
#pragma unroll
        for (int j = 0; j < 4; ++j) {
            float p = __expf(acc[kb][j] - mx);
            acc[kb][j] = p;
            s += p;
        }
    s += __shfl_xor(s, 16, 64);
    s += __shfl_xor(s, 32, 64);

    unsigned short* pw = &P[wid][fr][0];
#pragma unroll
    for (int kb = 0; kb < 15; ++kb) {
        ushort4 u;
        u.x = f2bf(acc[kb][0]); u.y = f2bf(acc[kb][1]);
        u.z = f2bf(acc[kb][2]); u.w = f2bf(acc[kb][3]);
        *(ushort4*)(pw + kb * 16 + fg * 4) = u;
    }
    {
        ushort4 z = {0, 0, 0, 0};
        *(ushort4*)(pw + 240 + fg * 4) = z;
    }

    f32x4 oacc[4] = {};
    const unsigned short* vt_base = Vt + ((long)bv * DIM + h * DHD) * 256;
#pragma unroll
    for (int ks = 0; ks < 8; ++ks) {
        bf16x8 pf = *(const bf16x8*)(pw + ks * 32 + fg * 8);
#pragma unroll
        for (int n = 0; n < 4; ++n) {
            const unsigned short* vp = vt_base + (long)(n * 16 + fr) * 256 + ks * 32 + fg * 8;
            oacc[n] = MFMA16(*(const bf16x8*)vp, pf, oacc[n]);
        }
    }

    if (q0 + fr < nq) {
        float inv = ATT_SCALE / s;
        float* ob = outp + (long)(bv * nq + q0 + fr) * DIM + h * DHD;
#pragma unroll
        for (int n = 0; n < 4; ++n) {
            float4 o;
            o.x = oacc[n][0] * inv; o.y = oacc[n][1] * inv;
            o.z = oacc[n][2] * inv; o.w = oacc[n][3] * inv;
            *(float4*)(ob + n * 16 + fg * 4) = o;
        }
    }
}

// ----------------------------------------------------------------- launch ---
extern "C" void kernel_launch(void* const* d_in, const int* in_sizes, int n_in,
                              void* d_out, int out_size, void* d_ws, size_t ws_size,
                              hipStream_t stream)
{
    const float* vid_feat = (const float*)d_in[0];
    const float* txt_feat = (const float*)d_in[1];
    const int*   txt_mask = (const int*)d_in[3];
    const float* v2v_W = (const float*)d_in[4];
    const float* v2v_b = (const float*)d_in[5];
    const float* t2v_W = (const float*)d_in[6];
    const float* t2v_b = (const float*)d_in[7];
    const float* t2t_W = (const float*)d_in[8];
    const float* t2t_b = (const float*)d_in[9];
    const float* v2t_W = (const float*)d_in[10];
    const float* v2t_b = (const float*)d_in[11];

    char* ws = (char*)d_ws;
    unsigned short* vid_bf   = (unsigned short*)(ws);
    unsigned short* txt_bf   = (unsigned short*)(ws + 19267584L);
    unsigned short* Wv_bf    = (unsigned short*)(ws + 22413312L);
    unsigned short* Wt_bf    = (unsigned short*)(ws + 29491200L);
    unsigned short* proj_vid = (unsigned short*)(ws + 36569088L);
    unsigned short* proj_txt = (unsigned short*)(ws + 152174592L);
    unsigned short* Vt_v     = (unsigned short*)(ws + 171048960L);
    unsigned short* Vt_t     = (unsigned short*)(ws + 196214784L);

    const long WSL = 589824;  // one 768x768 weight slice (elements)
    CvtCfg cc;
    cc.src[0] = vid_feat; cc.dst[0] = vid_bf; cc.n4[0] = 9633792 / 4;
    cc.src[1] = txt_feat; cc.dst[1] = txt_bf; cc.n4[1] = 1572864 / 4;
    const float* wsrc_v[6] = { v2v_W, v2v_W + WSL, t2v_W, v2t_W + WSL,
                               v2v_W + 2 * WSL, v2t_W + 2 * WSL };
    const float* wsrc_t[6] = { t2v_W + WSL, t2v_W + 2 * WSL, v2t_W, t2t_W,
                               t2t_W + WSL, t2t_W + 2 * WSL };
    for (int i = 0; i < 6; ++i) {
        cc.src[2 + i] = wsrc_v[i]; cc.dst[2 + i] = Wv_bf + (long)i * WSL; cc.n4[2 + i] = WSL / 4;
        cc.src[8 + i] = wsrc_t[i]; cc.dst[8 + i] = Wt_bf + (long)i * WSL; cc.n4[8 + i] = WSL / 4;
    }
    cvt_bf16<<<dim3(2048, 14), 256, 0, stream>>>(cc);

    GemmCfg gc;
    gc.A[0] = vid_bf;  gc.W[0] = Wv_bf;  gc.out[0] = proj_vid;  gc.M[0] = 12544;
    gc.A[1] = txt_bf;  gc.W[1] = Wt_bf;  gc.out[1] = proj_txt;  gc.M[1] = 2048;
    const float* bsrc_v[6] = { v2v_b, v2v_b + 768, t2v_b, v2t_b + 768,
                               v2v_b + 1536, v2t_b + 1536 };
    const float* bsrc_t[6] = { t2v_b + 768, t2v_b + 1536, v2t_b, t2t_b,
                               t2t_b + 768, t2t_b + 1536 };
    for (int i = 0; i < 6; ++i) { gc.bias[0][i] = bsrc_v[i]; gc.bias[1][i] = bsrc_t[i]; }
    gemm_proj<<<dim3(98 * 36 + 16 * 36), 256, 0, stream>>>(gc, 98 * 36);

    const long PV = 12544L * 768, PT = 2048L * 768;
    TransCfg tc;
    tc.src[0] = proj_vid + 4 * PV;  tc.src[1] = proj_txt + 1 * PT;  tc.dst[0] = Vt_v;
    tc.src[2] = proj_vid + 5 * PV;  tc.src[3] = proj_txt + 5 * PT;  tc.dst[1] = Vt_t;
    transpose_v<<<dim3(16, 24, 64), 256, 0, stream>>>(tc);

    float* out_f = (float*)d_out;
    AttnCfg ac;
    ac.QA[0] = proj_vid + 0 * PV;  ac.QB[0] = proj_vid + 2 * PV;
    ac.KV[0] = proj_vid + 1 * PV;  ac.KT[0] = proj_txt + 0 * PT;
    ac.Vt[0] = Vt_v;               ac.outp[0] = out_f;
    ac.QA[1] = proj_txt + 2 * PT;  ac.QB[1] = proj_txt + 3 * PT;
    ac.KV[1] = proj_vid + 3 * PV;  ac.KT[1] = proj_txt + 4 * PT;
    ac.Vt[1] = Vt_t;               ac.outp[1] = out_f + 9633792;
    attn_kernel<<<dim3(64, 12, 5), 256, 0, stream>>>(ac, txt_mask);
}

// Round 12
// 271.630 us; speedup vs baseline: 1.5988x; 1.1224x over previous
//
#include <hip/hip_runtime.h>

#define NBV 64
#define HWN 196
#define LTN 32
#define DIM 768
#define NH 12
#define DHD 64
#define ATT_SCALE 0.125f

typedef __attribute__((ext_vector_type(8))) __bf16 bf16x8;
typedef __attribute__((ext_vector_type(4))) float f32x4;

static __device__ __forceinline__ unsigned short f2bf(float f) {
    union { float f; unsigned u; } v; v.f = f;
    unsigned r = v.u + 0x7FFFu + ((v.u >> 16) & 1u);
    return (unsigned short)(r >> 16);
}

#define MFMA16(a, b, c) __builtin_amdgcn_mfma_f32_16x16x32_bf16((a), (b), (c), 0, 0, 0)
#define GLOAD_LDS16(g, l)                                                      \
    __builtin_amdgcn_global_load_lds(                                          \
        (const __attribute__((address_space(1))) void*)(g),                    \
        (__attribute__((address_space(3))) void*)(l), 16, 0, 0)

// Shared K-tile compute body (R3-exact): 12 ds_read_b128 + 32 MFMA, setprio.
__device__ __forceinline__ void compute_tile(const unsigned short* sa,
                                             const unsigned short* sb,
                                             f32x4 (&acc)[8][4])
{
    bf16x8 af[8], bg[4];
#pragma unroll
    for (int m = 0; m < 4; ++m) af[m] = *(const bf16x8*)(sa + m * 512);
#pragma unroll
    for (int n = 0; n < 4; ++n) bg[n] = *(const bf16x8*)(sb + n * 512);
#pragma unroll
    for (int m = 4; m < 8; ++m) af[m] = *(const bf16x8*)(sa + m * 512);
    __builtin_amdgcn_s_setprio(1);
#pragma unroll
    for (int m = 0; m < 4; ++m)
#pragma unroll
        for (int n = 0; n < 4; ++n)
            acc[m][n] = MFMA16(bg[n], af[m], acc[m][n]);
    __builtin_amdgcn_s_setprio(0);
    __builtin_amdgcn_s_setprio(1);
#pragma unroll
    for (int m = 4; m < 8; ++m)
#pragma unroll
        for (int n = 0; n < 4; ++n)
            acc[m][n] = MFMA16(bg[n], af[m], acc[m][n]);
    __builtin_amdgcn_s_setprio(0);
}

// ---------------------------------------------------------------- convert ---
struct CvtCfg {
    const float* src[14];
    unsigned short* dst[14];
    int n4[14];
};

__global__ __launch_bounds__(256) void cvt_bf16(CvtCfg cfg) {
    const int e = blockIdx.y;
    const float4* s = (const float4*)cfg.src[e];
    unsigned short* d = cfg.dst[e];
    const int n4 = cfg.n4[e];
    for (int i = blockIdx.x * 256 + threadIdx.x; i < n4; i += gridDim.x * 256) {
        float4 v = s[i];
        ushort4 o;
        o.x = f2bf(v.x); o.y = f2bf(v.y); o.z = f2bf(v.z); o.w = f2bf(v.w);
        *(ushort4*)(d + (long)i * 4) = o;
    }
}

// ------------------------------------------------------------------- GEMM ---
// R3-exact (best measured: 138.3 us, replay-safe through R9).  256x256 tile,
// BK=32, 8 waves, 4 slots, depth-3 prefetch, vmcnt(8), one barrier/K-tile,
// C^T frags, LDS-staged coalesced epilogue.
struct GemmCfg {
    const unsigned short* A[2];
    const unsigned short* W[2];
    unsigned short* out[2];
    const float* bias[2][6];
    int M[2];
};

__global__ __launch_bounds__(512, 2) void gemm_proj(GemmCfg cfg, int nb0)
{
    __shared__ __align__(16) unsigned short lds[65536];   // 4 slots x 32 KiB
    const int tid = threadIdx.x;
    const int lane = tid & 63, wid = tid >> 6;
    const int wm = wid >> 2, wn = wid & 3;
    const int fr = lane & 15, fg = lane >> 4;

    const int nwg = gridDim.x;
    const int orig = blockIdx.x;
    const int q = nwg >> 3, r = nwg & 7;
    const int xcd = orig & 7, lid = orig >> 3;
    const int wg = (xcd < r ? xcd * (q + 1) : r * (q + 1) + (xcd - r) * q) + lid;

    const int set = wg >= nb0;
    const int local = wg - (set ? nb0 : 0);
    const int mt = local / 18, nt = local - mt * 18;
    const int m0 = mt * 256, n0 = nt * 256;
    const int M = cfg.M[set];
    const unsigned short* __restrict__ A = cfg.A[set];
    const unsigned short* __restrict__ W = cfg.W[set];

    const int srow = tid >> 2;
    const int sxor = ((tid & 3) ^ ((tid >> 3) & 3)) * 8;
    const unsigned short* aSrc = A + (long)(m0 + srow) * DIM + sxor;
    const unsigned short* bSrc = W + (long)(n0 + srow) * DIM + sxor;
    unsigned short* ldst = lds + tid * 8;

    const int rxor = (fg ^ ((fr >> 1) & 3)) * 8;
    const int aoff = (wm * 128 + fr) * 32 + rxor;
    const int boff = 8192 + (wn * 64 + fr) * 32 + rxor;

    f32x4 acc[8][4] = {};   // acc[m][n][j] = C[m*16+fr][n*16+fg*4+j]  (C^T frag)

#define STAGE(t, s) do {                                                       \
    const unsigned short* _a = aSrc + (t) * 32;                                \
    const unsigned short* _b = bSrc + (t) * 32;                                \
    unsigned short* _d = ldst + (s) * 16384;                                   \
    GLOAD_LDS16(_a, _d);                                                       \
    GLOAD_LDS16(_a + 98304, _d + 4096);                                        \
    GLOAD_LDS16(_b, _d + 8192);                                                \
    GLOAD_LDS16(_b + 98304, _d + 12288);                                       \
} while (0)

    STAGE(0, 0); STAGE(1, 1); STAGE(2, 2);
#pragma unroll 1
    for (int t = 0; t < 21; ++t) {                 // K=768 -> 24 tiles of 32
        asm volatile("s_waitcnt vmcnt(8)" ::: "memory");   // tile t landed
        __builtin_amdgcn_s_barrier();
        STAGE(t + 3, (t + 3) & 3);                 // slot of tile t-1: free
        {
            const unsigned short* base = lds + (t & 3) * 16384;
            compute_tile(base + aoff, base + boff, acc);
        }
    }
    asm volatile("s_waitcnt vmcnt(8)" ::: "memory");
    __builtin_amdgcn_s_barrier();
    { const unsigned short* base = lds + 16384;     compute_tile(base + aoff, base + boff, acc); }
    asm volatile("s_waitcnt vmcnt(4)" ::: "memory");
    __builtin_amdgcn_s_barrier();
    { const unsigned short* base = lds + 2 * 16384; compute_tile(base + aoff, base + boff, acc); }
    asm volatile("s_waitcnt vmcnt(0)" ::: "memory");
    __builtin_amdgcn_s_barrier();
    { const unsigned short* base = lds + 3 * 16384; compute_tile(base + aoff, base + boff, acc); }

#undef STAGE

    // ---- epilogue: bias + bf16, staged through LDS for coalesced stores ----
    const int w = nt / 3;
    const int nlb = (nt - w * 3) * 256;
    const float* bp = cfg.bias[set][w];
    unsigned short* op = cfg.out[set] + (long)w * M * DIM;
    const int colL = wn * 64;
    asm volatile("" ::: "memory");
    __builtin_amdgcn_s_barrier();                  // LDS reuse for C
#pragma unroll
    for (int p = 0; p < 2; ++p) {
        if (wm == p) {
#pragma unroll
            for (int n = 0; n < 4; ++n) {
                float4 b4 = *(const float4*)(bp + nlb + colL + n * 16 + fg * 4);
#pragma unroll
                for (int m = 0; m < 8; ++m) {
                    ushort4 u;
                    u.x = f2bf(acc[m][n][0] + b4.x);
                    u.y = f2bf(acc[m][n][1] + b4.y);
                    u.z = f2bf(acc[m][n][2] + b4.z);
                    u.w = f2bf(acc[m][n][3] + b4.w);
                    *(ushort4*)&lds[(m * 16 + fr) * 264 + colL + n * 16 + fg * 4] = u;
                }
            }
        }
        __builtin_amdgcn_s_barrier();
#pragma unroll
        for (int i = 0; i < 8; ++i) {
            int chunk = tid + i * 512;             // 4096 chunks = 128x256
            int rr = chunk >> 5, cb = chunk & 31;
            bf16x8 v = *(const bf16x8*)&lds[rr * 264 + cb * 8];
            *(bf16x8*)(op + (long)(m0 + p * 128 + rr) * DIM + nlb + cb * 8) = v;
        }
        if (p == 0) __builtin_amdgcn_s_barrier();
    }
}

// -------------------------------------------------------------- transpose ---
struct TransCfg {
    const unsigned short* src[4];
    unsigned short* dst[4];
};

__global__ __launch_bounds__(256) void transpose_v(TransCfg cfg)
{
    __shared__ unsigned short t[32][33];
    const int x = blockIdx.x;
    const int which = x >> 3;
    const int xi = x & 7;
    const int istxt = (xi == 7);
    const unsigned short* src = cfg.src[which * 2 + istxt];
    unsigned short* dst = cfg.dst[which];
    const int nrows = istxt ? LTN : HWN;
    const int colbase = istxt ? 208 : 0;
    const int rt = istxt ? 0 : xi;

    const int bv = blockIdx.z, dt = blockIdx.y;
    const int tx = threadIdx.x & 31, ty = threadIdx.x >> 5;
#pragma unroll
    for (int i = 0; i < 4; ++i) {
        int r = rt * 32 + ty + i * 8;
        t[ty + i * 8][tx] = (r < nrows)
            ? src[(long)(bv * nrows + r) * DIM + dt * 32 + tx] : (unsigned short)0;
    }
    __syncthreads();
#pragma unroll
    for (int i = 0; i < 4; ++i) {
        int d = dt * 32 + ty + i * 8;
        int rr = rt * 32 + tx;
        if (rr < nrows)
            dst[(long)(bv * DIM + d) * 256 + colbase + rr] = t[tx][ty + i * 8];
    }
}

// -------------------------------------------------------------- attention ---
// R6-R10 known-good structure (one q-tile per wave, z=5 grid, P wave-private,
// no barriers) + early exit for waves whose entire q-tile is out of range
// (video z=3 wid>=1: q0=208/224/240; text wid>=2) — safe since no barriers.
struct AttnCfg {
    const unsigned short* QA[2];
    const unsigned short* QB[2];
    const unsigned short* KV[2];
    const unsigned short* KT[2];
    const unsigned short* Vt[2];
    float* outp[2];
};

__global__ __launch_bounds__(256, 2) void attn_kernel(AttnCfg cfg,
                                                      const int* __restrict__ tmask)
{
    __shared__ __align__(16) unsigned short P[4][16][264];
    const int tid = threadIdx.x, lane = tid & 63, wid = tid >> 6;
    const int bv = blockIdx.x, h = blockIdx.y;
    const int b = bv >> 4;
    const int sel = (blockIdx.z == 4);
    const int nq = sel ? LTN : HWN;
    const unsigned short* QA = cfg.QA[sel];
    const unsigned short* QB = cfg.QB[sel];
    const unsigned short* KV = cfg.KV[sel];
    const unsigned short* KT = cfg.KT[sel];
    const unsigned short* Vt = cfg.Vt[sel];
    float* outp = cfg.outp[sel];
    const int q0 = (sel ? 0 : blockIdx.z * 64) + wid * 16;
    const int fr = lane & 15, fg = lane >> 4;

    if (q0 >= ((nq + 15) & ~15)) return;           // whole q-tile out of range

    int qr = q0 + fr; if (qr > nq - 1) qr = nq - 1;
    const unsigned short* qa_p = QA + (long)(bv * nq + qr) * DIM + h * DHD;
    const unsigned short* qb_p = QB + (long)(bv * nq + qr) * DIM + h * DHD;
    bf16x8 qa[2], qb[2];
#pragma unroll
    for (int kh = 0; kh < 2; ++kh) {
        qa[kh] = *(const bf16x8*)(qa_p + kh * 32 + fg * 8);
        qb[kh] = *(const bf16x8*)(qb_p + kh * 32 + fg * 8);
    }

    // S^T = K * Q^T :  acc[kb][j] = S[k = kb*16 + fg*4 + j][q = fr]
    f32x4 acc[15];
#pragma unroll
    for (int kb = 0; kb < 13; ++kb) {
        int kr = kb * 16 + fr; if (kr > HWN - 1) kr = HWN - 1;
        const unsigned short* kp = KV + (long)(bv * HWN + kr) * DIM + h * DHD;
        f32x4 c = {0.f, 0.f, 0.f, 0.f};
        c = MFMA16(*(const bf16x8*)(kp + fg * 8), qa[0], c);
        c = MFMA16(*(const bf16x8*)(kp + 32 + fg * 8), qa[1], c);
        acc[kb] = c;
    }
#pragma unroll
    for (int kb = 13; kb < 15; ++kb) {
        int kr = (kb - 13) * 16 + fr;
        const unsigned short* kp = KT + (long)(bv * LTN + kr) * DIM + h * DHD;
        f32x4 c = {0.f, 0.f, 0.f, 0.f};
        c = MFMA16(*(const bf16x8*)(kp + fg * 8), qb[0], c);
        c = MFMA16(*(const bf16x8*)(kp + 32 + fg * 8), qb[1], c);
        acc[kb] = c;
    }

    // masks: real masked -> -10000 (reference semantics), pad -> -3e38
    int tm = tmask[b * LTN + (lane & 31)];         // coalesced; lanes 0..31 hold row
    bool vq = true;
    if (sel) {
        int qi = q0 + fr; if (qi > LTN - 1) qi = LTN - 1;
        vq = __shfl(tm, qi, 64) != 0;
    }
#pragma unroll
    for (int kb = 0; kb < 15; ++kb) {
#pragma unroll
        for (int j = 0; j < 4; ++j) {
            int c = kb * 16 + fg * 4 + j;
            bool kreal = (c < HWN) || (c >= 208);
            bool kvalid = true;
            if (c >= 208) kvalid = __shfl(tm, c - 208, 64) != 0;
            float l = acc[kb][j];
            if (!kreal) l = -3.0e38f;
            else if (!(kvalid && vq)) l = -10000.0f;
            acc[kb][j] = l;
        }
    }

    // row softmax (row = q = fr, spread across the 4 fg groups)
    float mx = -3.0e38f;
#pragma unroll
    for (int kb = 0; kb < 15; ++kb)
#pragma unroll
        for (int j = 0; j < 4; ++j) mx = fmaxf(mx, acc[kb][j]);
    mx = fmaxf(mx, __shfl_xor(mx, 16, 64));
    mx = fmaxf(mx, __shfl_xor(mx, 32, 64));
    float s = 0.f;
#pragma unroll
    for (int kb = 0; kb < 15; ++kb)
#pragma unroll
        for (int j = 0; j < 4; ++j) {
            float p = __expf(acc[kb][j] - mx);
            acc[kb][j] = p;
            s += p;
        }
    s += __shfl_xor(s, 16, 64);
    s += __shfl_xor(s, 32, 64);

    // P[q=fr][k] bf16, stride 264: b64 writes, conflict-free, wave-private
    unsigned short* pw = &P[wid][fr][0];
#pragma unroll
    for (int kb = 0; kb < 15; ++kb) {
        ushort4 u;
        u.x = f2bf(acc[kb][0]); u.y = f2bf(acc[kb][1]);
        u.z = f2bf(acc[kb][2]); u.w = f2bf(acc[kb][3]);
        *(ushort4*)(pw + kb * 16 + fg * 4) = u;
    }
    {
        ushort4 z = {0, 0, 0, 0};
        *(ushort4*)(pw + 240 + fg * 4) = z;
    }

    // O^T = V^T * P^T :  oacc[n][j] = O[d = n*16 + fg*4 + j][q = fr]
    f32x4 oacc[4] = {};
    const unsigned short* vt_base = Vt + ((long)bv * DIM + h * DHD) * 256;
#pragma unroll
    for (int ks = 0; ks < 8; ++ks) {
        bf16x8 pf = *(const bf16x8*)(pw + ks * 32 + fg * 8);
#pragma unroll
        for (int n = 0; n < 4; ++n) {
            const unsigned short* vp = vt_base + (long)(n * 16 + fr) * 256 + ks * 32 + fg * 8;
            oacc[n] = MFMA16(*(const bf16x8*)vp, pf, oacc[n]);
        }
    }

    if (q0 + fr < nq) {
        float inv = ATT_SCALE / s;
        float* ob = outp + (long)(bv * nq + q0 + fr) * DIM + h * DHD;
#pragma unroll
        for (int n = 0; n < 4; ++n) {
            float4 o;
            o.x = oacc[n][0] * inv; o.y = oacc[n][1] * inv;
            o.z = oacc[n][2] * inv; o.w = oacc[n][3] * inv;
            *(float4*)(ob + n * 16 + fg * 4) = o;
        }
    }
}

// ----------------------------------------------------------------- launch ---
extern "C" void kernel_launch(void* const* d_in, const int* in_sizes, int n_in,
                              void* d_out, int out_size, void* d_ws, size_t ws_size,
                              hipStream_t stream)
{
    const float* vid_feat = (const float*)d_in[0];
    const float* txt_feat = (const float*)d_in[1];
    const int*   txt_mask = (const int*)d_in[3];
    const float* v2v_W = (const float*)d_in[4];
    const float* v2v_b = (const float*)d_in[5];
    const float* t2v_W = (const float*)d_in[6];
    const float* t2v_b = (const float*)d_in[7];
    const float* t2t_W = (const float*)d_in[8];
    const float* t2t_b = (const float*)d_in[9];
    const float* v2t_W = (const float*)d_in[10];
    const float* v2t_b = (const float*)d_in[11];

    char* ws = (char*)d_ws;
    unsigned short* vid_bf   = (unsigned short*)(ws);
    unsigned short* txt_bf   = (unsigned short*)(ws + 19267584L);
    unsigned short* Wv_bf    = (unsigned short*)(ws + 22413312L);
    unsigned short* Wt_bf    = (unsigned short*)(ws + 29491200L);
    unsigned short* proj_vid = (unsigned short*)(ws + 36569088L);
    unsigned short* proj_txt = (unsigned short*)(ws + 152174592L);
    unsigned short* Vt_v     = (unsigned short*)(ws + 171048960L);
    unsigned short* Vt_t     = (unsigned short*)(ws + 196214784L);

    const long WSL = 589824;  // one 768x768 weight slice (elements)
    CvtCfg cc;
    cc.src[0] = vid_feat; cc.dst[0] = vid_bf; cc.n4[0] = 9633792 / 4;
    cc.src[1] = txt_feat; cc.dst[1] = txt_bf; cc.n4[1] = 1572864 / 4;
    const float* wsrc_v[6] = { v2v_W, v2v_W + WSL, t2v_W, v2t_W + WSL,
                               v2v_W + 2 * WSL, v2t_W + 2 * WSL };
    const float* wsrc_t[6] = { t2v_W + WSL, t2v_W + 2 * WSL, v2t_W, t2t_W,
                               t2t_W + WSL, t2t_W + 2 * WSL };
    for (int i = 0; i < 6; ++i) {
        cc.src[2 + i] = wsrc_v[i]; cc.dst[2 + i] = Wv_bf + (long)i * WSL; cc.n4[2 + i] = WSL / 4;
        cc.src[8 + i] = wsrc_t[i]; cc.dst[8 + i] = Wt_bf + (long)i * WSL; cc.n4[8 + i] = WSL / 4;
    }
    cvt_bf16<<<dim3(2048, 14), 256, 0, stream>>>(cc);

    GemmCfg gc;
    gc.A[0] = vid_bf;  gc.W[0] = Wv_bf;  gc.out[0] = proj_vid;  gc.M[0] = 12544;
    gc.A[1] = txt_bf;  gc.W[1] = Wt_bf;  gc.out[1] = proj_txt;  gc.M[1] = 2048;
    const float* bsrc_v[6] = { v2v_b, v2v_b + 768, t2v_b, v2t_b + 768,
                               v2v_b + 1536, v2t_b + 1536 };
    const float* bsrc_t[6] = { t2v_b + 768, t2v_b + 1536, v2t_b, t2t_b,
                               t2t_b + 768, t2t_b + 1536 };
    for (int i = 0; i < 6; ++i) { gc.bias[0][i] = bsrc_v[i]; gc.bias[1][i] = bsrc_t[i]; }
    gemm_proj<<<dim3(49 * 18 + 8 * 18), 512, 0, stream>>>(gc, 49 * 18);

    const long PV = 12544L * 768, PT = 2048L * 768;
    TransCfg tc;
    tc.src[0] = proj_vid + 4 * PV;  tc.src[1] = proj_txt + 1 * PT;  tc.dst[0] = Vt_v;
    tc.src[2] = proj_vid + 5 * PV;  tc.src[3] = proj_txt + 5 * PT;  tc.dst[1] = Vt_t;
    transpose_v<<<dim3(16, 24, 64), 256, 0, stream>>>(tc);

    float* out_f = (float*)d_out;
    AttnCfg ac;
    // video: QA=Qv(w0), QB=Qt2v(w2), KV=Kv(w1), KT=Kt2v(txt w0)
    ac.QA[0] = proj_vid + 0 * PV;  ac.QB[0] = proj_vid + 2 * PV;
    ac.KV[0] = proj_vid + 1 * PV;  ac.KT[0] = proj_txt + 0 * PT;
    ac.Vt[0] = Vt_v;               ac.outp[0] = out_f;
    // text: QA=Qv2t(txt w2), QB=Qt2t(txt w3), KV=Kv2t(vid w3), KT=Kt2t(txt w4)
    ac.QA[1] = proj_txt + 2 * PT;  ac.QB[1] = proj_txt + 3 * PT;
    ac.KV[1] = proj_vid + 3 * PV;  ac.KT[1] = proj_txt + 4 * PT;
    ac.Vt[1] = Vt_t;               ac.outp[1] = out_f + 9633792;
    attn_kernel<<<dim3(64, 12, 5), 256, 0, stream>>>(ac, txt_mask);
}